// Round 10
// baseline (391.237 us; speedup 1.0000x reference)
//
#include <hip/hip_runtime.h>

typedef float f32x4 __attribute__((ext_vector_type(4)));
typedef __bf16 bf16x8 __attribute__((ext_vector_type(8)));
typedef short s16x8 __attribute__((ext_vector_type(8)));

// Problem constants
#define NPOS   524288         // 8*16*64*64
#define KCODES 512
#define CDIM   64
#define THW    65536          // 16*64*64
#define MPOS   256            // positions per block
#define NTHR   512            // 8 waves
#define NCH    32             // e-chunks of 16 codes
#define EPS2   4e-4f          // 2*epsilon certification threshold (proven R9)

// out layout (float32): [0, 33554432) quantized BCTHW; [33554432] loss; [33554433,+524288) indices
#define QOUT_N   33554432L
#define LOSSOFF  33554432L
#define IDX_OFF  33554433L

// ws: 0: double loss; 256: float eeg[512]; 4096: ushort ehi_g[8][512][8]; 69632: ushort emid_g[8][512][8]

__device__ inline unsigned int bf16_rne(unsigned int xb) {   // RN-even fp32->bf16 (no NaN/inf in data)
    return (xb + 0x7fffu + ((xb >> 16) & 1u)) >> 16;
}

#define GLOAD16(gp, lp) __builtin_amdgcn_global_load_lds( \
    (const __attribute__((address_space(1))) void*)(gp), \
    (__attribute__((address_space(3))) void*)(lp), 16, 0, 0)

__device__ inline f32x4 mf(s16x8 a, s16x8 b, f32x4 c) {
    return __builtin_amdgcn_mfma_f32_16x16x32_bf16(
        __builtin_bit_cast(bf16x8, a), __builtin_bit_cast(bf16x8, b), c, 0, 0, 0);
}

// bit-exact distance key (same chain as passing R4/R9 kernels): (dist_bits<<32)|code
__device__ inline unsigned long long exact_key(const float* a, const float* ffl,
                                               const float* eel, const float* __restrict__ emb,
                                               int pos, int q) {
    const float* er = emb + (long)q * 64;
    float acc = __fmul_rn(a[pos], er[0]);
    #pragma unroll
    for (int c = 1; c < 64; ++c) acc = __fmaf_rn(a[c * 256 + pos], er[c], acc);
    float t1 = __fadd_rn(ffl[pos], eel[q]);
    float d  = __fmaf_rn(acc, -2.0f, t1);
    return ((unsigned long long)__float_as_uint(d) << 32) | (unsigned)q;
}

// ---------- prep: exact ee[q] (numpy pairwise-8) + bf16 hi/mid split codebook ----------
extern "C" __global__ void vq_prep(const float* __restrict__ emb, float* __restrict__ ee,
                                   unsigned short* __restrict__ ehi, unsigned short* __restrict__ emid) {
    int q = threadIdx.x;               // 512 threads
    const float* er = emb + q * 64;
    float r[8];
    #pragma unroll
    for (int j = 0; j < 8; ++j) { float v = er[j]; r[j] = __fmul_rn(v, v); }
    #pragma unroll
    for (int t = 1; t < 8; ++t)
        #pragma unroll
        for (int j = 0; j < 8; ++j) { float v = er[t * 8 + j]; r[j] = __fadd_rn(r[j], __fmul_rn(v, v)); }
    float s0 = __fadd_rn(__fadd_rn(r[0], r[1]), __fadd_rn(r[2], r[3]));
    float s1 = __fadd_rn(__fadd_rn(r[4], r[5]), __fadd_rn(r[6], r[7]));
    ee[q] = __fadd_rn(s0, s1);
    #pragma unroll
    for (int c = 0; c < 64; ++c) {
        float x = er[c];
        unsigned int hb = bf16_rne(__float_as_uint(x));
        float hif = __uint_as_float(hb << 16);
        float m = __fsub_rn(x, hif);
        unsigned int mb = bf16_rne(__float_as_uint(m));
        long o = ((long)(c >> 3) * 512 + q) * 8 + (c & 7);   // [kg][code][8]
        ehi[o]  = (unsigned short)hb;
        emid[o] = (unsigned short)mb;
    }
}

// stage one 16-code e-chunk (4 KB: hi+mid) into LDS buffer buf; 256 threads x 1 GLOAD16
__device__ inline void stage_e(int tid, int ch2, int buf,
                               const unsigned short* __restrict__ ehi_g,
                               const unsigned short* __restrict__ emid_g,
                               unsigned short* ehc, unsigned short* emc) {
    if (tid < 256) {
        int t = tid & 127, kg = t >> 4, ci = t & 15;
        const unsigned short* src = ((tid & 128) ? emid_g : ehi_g)
                                  + ((long)kg * 512 + ch2 * 16 + ci) * 8;
        unsigned short* dst = ((tid & 128) ? emc : ehc) + buf * 1024 + (kg * 16 + ci) * 8;
        GLOAD16(src, dst);
    }
}

// LDS layout (bytes):
//   a     : 0      .. 65536   fp32 [64][256]
//   ehc   : 65536  .. +4096   ushort [2][8][16][8]   (double-buffered hi chunk)
//   emc   : 69632  .. +4096   ushort [2][8][16][8]   (double-buffered mid chunk)
//   eel   : 73728  .. +2048   float [512]
//   ffl   : 75776  .. +1024   float [256]
//   kminl : 76800  .. +1024   int [256]
//   wl    : 77824  .. +1024   int [256]
//   wcnt  : 78848  (+8) | wred: 78856 (+64) | wsum: 78920 (+64)  -> total 78984

extern "C" __global__ __launch_bounds__(NTHR, 2)
void vq_main(const float* __restrict__ x, const float* __restrict__ emb,
             float* __restrict__ out, double* __restrict__ lossws,
             const float* __restrict__ eeg,
             const unsigned short* __restrict__ ehi_g,
             const unsigned short* __restrict__ emid_g) {
    extern __shared__ char smem[];
    float*          a     = (float*)smem;
    unsigned short* ehc   = (unsigned short*)(smem + 65536);
    unsigned short* emc   = (unsigned short*)(smem + 69632);
    float*          eel   = (float*)(smem + 73728);
    float*          ffl   = (float*)(smem + 75776);
    int*            kminl = (int*)(smem + 76800);
    int*            wl    = (int*)(smem + 77824);
    int*            wcnt  = (int*)(smem + 78848);
    unsigned long long* wred = (unsigned long long*)(smem + 78856);
    double*         wsum  = (double*)(smem + 78920);

    const int tid  = threadIdx.x;
    const int lane = tid & 63;
    const int w    = tid >> 6;                    // wave 0..7 -> positions [w*32, w*32+32)
    const int blk  = blockIdx.x;
    const int b    = blk >> 8;                    // 256 blocks per batch element
    const int r0   = (blk & 255) << 8;
    const long n0  = (long)blk * MPOS;

    if (tid == 0) *wcnt = 0;

    // ---- phase 1: stage x-tile [64][256] + eel + e-chunks 0,1 (linear-dest gload_lds)
    const float* xb = x + (long)b * CDIM * THW + r0;
    #pragma unroll
    for (int k = 0; k < 8; ++k) {
        int g = tid + NTHR * k;                   // 16B-unit 0..4095
        int c = g >> 6, p4 = g & 63;
        GLOAD16(xb + (long)c * THW + p4 * 4, a + g * 4);
    }
    if (tid < 128) GLOAD16(eeg + tid * 4, eel + tid * 4);
    stage_e(tid, 0, 0, ehi_g, emid_g, ehc, emc);
    stage_e(tid, 1, 1, ehi_g, emid_g, ehc, emc);
    __syncthreads();   // full drain (one-time); a, eel, chunks 0,1 ready

    // ---- phase 2a: ff[p] exact (numpy pairwise-8; proven)
    if (tid < 256) {
        float rr[8];
        #pragma unroll
        for (int j = 0; j < 8; ++j) { float v = a[j * 256 + tid]; rr[j] = __fmul_rn(v, v); }
        #pragma unroll
        for (int t = 1; t < 8; ++t)
            #pragma unroll
            for (int j = 0; j < 8; ++j) {
                float v = a[(t * 8 + j) * 256 + tid];
                rr[j] = __fadd_rn(rr[j], __fmul_rn(v, v));
            }
        float s0 = __fadd_rn(__fadd_rn(rr[0], rr[1]), __fadd_rn(rr[2], rr[3]));
        float s1 = __fadd_rn(__fadd_rn(rr[4], rr[5]), __fadd_rn(rr[6], rr[7]));
        ffl[tid] = __fadd_rn(s0, s1);
    }

    // ---- phase 2b: per-wave A-fragments built in registers (split done in-lane)
    s16x8 fah[2][2], fam[2][2];
    #pragma unroll
    for (int mt = 0; mt < 2; ++mt)
        #pragma unroll
        for (int ks = 0; ks < 2; ++ks) {
            int kg  = ks * 4 + (lane >> 4);
            int pin = w * 32 + mt * 16 + (lane & 15);
            s16x8 hv, mv;
            #pragma unroll
            for (int j = 0; j < 8; ++j) {
                float xv = a[(kg * 8 + j) * 256 + pin];
                unsigned int hb = bf16_rne(__float_as_uint(xv));
                float hif = __uint_as_float(hb << 16);
                float m = __fsub_rn(xv, hif);
                unsigned int mb = bf16_rne(__float_as_uint(m));
                hv[j] = (short)hb; mv[j] = (short)mb;
            }
            fah[mt][ks] = hv; fam[mt][ks] = mv;
        }
    __syncthreads();   // ffl ready for all (and A-frag reads of `a` done)

    float ffv[8];
    #pragma unroll
    for (int mt = 0; mt < 2; ++mt)
        #pragma unroll
        for (int rg = 0; rg < 4; ++rg)
            ffv[mt * 4 + rg] = ffl[w * 32 + mt * 16 + (lane >> 4) * 4 + rg];

    unsigned long long u1[8], u2[8];
    #pragma unroll
    for (int s = 0; s < 8; ++s) { u1[s] = ~0ull; u2[s] = ~0ull; }

    // ---- phase 4: MFMA distance scan, 32 chunks x 16 codes, dbuf + counted vmcnt
    const int kg0 = lane >> 4, cin = lane & 15;
    #pragma unroll 1
    for (int ch = 0; ch < NCH; ++ch) {
        const int buf = ch & 1;
        const unsigned short* eh = ehc + buf * 1024;
        const unsigned short* em = emc + buf * 1024;
        s16x8 bh0 = *(const s16x8*)(eh + ((kg0    ) * 16 + cin) * 8);
        s16x8 bh1 = *(const s16x8*)(eh + ((kg0 + 4) * 16 + cin) * 8);
        s16x8 bm0 = *(const s16x8*)(em + ((kg0    ) * 16 + cin) * 8);
        s16x8 bm1 = *(const s16x8*)(em + ((kg0 + 4) * 16 + cin) * 8);
        unsigned code = ch * 16 + cin;
        float eev = eel[code];
        #pragma unroll
        for (int mt = 0; mt < 2; ++mt) {
            f32x4 acc = {0.f, 0.f, 0.f, 0.f};
            acc = mf(fah[mt][0], bh0, acc);
            acc = mf(fah[mt][1], bh1, acc);
            acc = mf(fah[mt][0], bm0, acc);
            acc = mf(fah[mt][1], bm1, acc);
            acc = mf(fam[mt][0], bh0, acc);
            acc = mf(fam[mt][1], bh1, acc);
            #pragma unroll
            for (int rg = 0; rg < 4; ++rg) {
                int s = mt * 4 + rg;
                float t1 = __fadd_rn(ffv[s], eev);
                float d  = __fmaf_rn(acc[rg], -2.0f, t1);
                unsigned long long key = ((unsigned long long)__float_as_uint(d) << 32) | code;
                bool c1 = key < u1[s];
                unsigned long long nu2 = key < u2[s] ? key : u2[s];
                u2[s] = c1 ? u1[s] : nu2;
                u1[s] = c1 ? key : u1[s];
            }
        }
        __builtin_amdgcn_s_barrier();            // all reads of buf done
        if (ch < NCH - 2)
            stage_e(tid, ch + 2, buf, ehi_g, emid_g, ehc, emc);
        if (ch < NCH - 2) {
            asm volatile("s_waitcnt vmcnt(1)" ::: "memory");  // chunk ch+1 landed; ch+2 in flight
            __builtin_amdgcn_s_barrier();
        } else if (ch < NCH - 1) {
            asm volatile("s_waitcnt vmcnt(0)" ::: "memory");  // last chunk landed
            __builtin_amdgcn_s_barrier();
        }
    }

    // ---- phase 5: cross-lane top-3 merge (within 16 code-lanes) + certify (proven R9)
    #pragma unroll
    for (int s = 0; s < 8; ++s) {
        unsigned long long v1 = u1[s], v2 = u2[s];
        #pragma unroll
        for (int m = 1; m <= 8; m <<= 1) {
            unsigned long long p1 = __shfl_xor(v1, m, 64);
            unsigned long long p2 = __shfl_xor(v2, m, 64);
            unsigned long long lo  = v1 < p1 ? v1 : p1;
            unsigned long long hi  = v1 < p1 ? p1 : v1;
            unsigned long long mn2 = v2 < p2 ? v2 : p2;
            v1 = lo;
            v2 = hi < mn2 ? hi : mn2;
        }
        unsigned long long ex = (u1[s] != v1 && u1[s] != v2) ? u1[s]
                              : ((u2[s] != v1 && u2[s] != v2) ? u2[s] : ~0ull);
        #pragma unroll
        for (int m = 1; m <= 8; m <<= 1) {
            unsigned long long p = __shfl_xor(ex, m, 64);
            ex = p < ex ? p : ex;
        }
        if ((lane & 15) == 0) {
            int pos = w * 32 + (s >> 2) * 16 + (lane >> 4) * 4 + (s & 3);
            float d1 = __uint_as_float((unsigned)(v1 >> 32));
            float d2 = __uint_as_float((unsigned)(v2 >> 32));
            float d3 = __uint_as_float((unsigned)(ex >> 32));
            float thr = __fadd_rn(d1, EPS2);
            if (d2 > thr) {
                kminl[pos] = (int)(v1 & 0xffffffffu);
            } else if (d3 > thr) {
                unsigned long long ka = exact_key(a, ffl, eel, emb, pos, (int)(v1 & 0xffffffffu));
                unsigned long long kb = exact_key(a, ffl, eel, emb, pos, (int)(v2 & 0xffffffffu));
                unsigned long long km = ka < kb ? ka : kb;
                kminl[pos] = (int)(km & 0xffffffffu);
            } else {
                wl[atomicAdd(wcnt, 1)] = pos;
            }
        }
    }
    __syncthreads();

    // ---- phase 6: slow path — block-cooperative exact scan (512 threads = 512 codes)
    int nw = *wcnt;
    for (int i = 0; i < nw; ++i) {
        int pos = wl[i];
        unsigned long long key = exact_key(a, ffl, eel, emb, pos, tid);
        #pragma unroll
        for (int m = 1; m < 64; m <<= 1) {
            unsigned long long p = __shfl_xor(key, m, 64);
            key = p < key ? p : key;
        }
        if (lane == 0) wred[w] = key;
        __syncthreads();
        if (tid == 0) {
            unsigned long long km = wred[0];
            #pragma unroll
            for (int j = 1; j < 8; ++j) km = wred[j] < km ? wred[j] : km;
            kminl[pos] = (int)(km & 0xffffffffu);
        }
        __syncthreads();
    }

    // ---- indices out (as float)
    if (tid < 256) out[IDX_OFF + n0 + tid] = (float)kminl[tid];

    // ---- quantized out (straight-through) + loss partial (proven R4 epilogue)
    double lacc = 0.0;
    {
        const int col = (tid & 63) * 4;
        int iv[4];
        #pragma unroll
        for (int jj = 0; jj < 4; ++jj) iv[jj] = kminl[col + jj];
        float* ob = out + (long)b * CDIM * THW + r0;
        #pragma unroll
        for (int k = 0; k < 8; ++k) {
            int c = (tid >> 6) + 8 * k;
            float4 xv = *(const float4*)(a + c * 256 + col);
            float4 ov;
            float q0 = emb[iv[0] * 64 + c];
            float d0 = __fsub_rn(q0, xv.x); ov.x = __fadd_rn(xv.x, d0); lacc += (double)__fmul_rn(d0, d0);
            float q1 = emb[iv[1] * 64 + c];
            float d1 = __fsub_rn(q1, xv.y); ov.y = __fadd_rn(xv.y, d1); lacc += (double)__fmul_rn(d1, d1);
            float q2 = emb[iv[2] * 64 + c];
            float d2 = __fsub_rn(q2, xv.z); ov.z = __fadd_rn(xv.z, d2); lacc += (double)__fmul_rn(d2, d2);
            float q3 = emb[iv[3] * 64 + c];
            float d3 = __fsub_rn(q3, xv.w); ov.w = __fadd_rn(xv.w, d3); lacc += (double)__fmul_rn(d3, d3);
            *(float4*)(ob + (long)c * THW + col) = ov;
        }
    }
    #pragma unroll
    for (int m = 1; m < 64; m <<= 1) lacc += __shfl_xor(lacc, m, 64);
    if (lane == 0) wsum[w] = lacc;
    __syncthreads();
    if (tid == 0) {
        double s = 0.0;
        #pragma unroll
        for (int i = 0; i < 8; ++i) s += wsum[i];
        atomicAdd(lossws, s);
    }
}

extern "C" __global__ void vq_finalize(const double* __restrict__ lossws,
                                       float* __restrict__ out) {
    if (threadIdx.x == 0) {
        float m = (float)(lossws[0] / (double)QOUT_N);
        out[LOSSOFF] = __fadd_rn(m, __fmul_rn(0.025f, m));
    }
}

extern "C" void kernel_launch(void* const* d_in, const int* in_sizes, int n_in,
                              void* d_out, int out_size, void* d_ws, size_t ws_size,
                              hipStream_t stream) {
    const float* x   = (const float*)d_in[0];
    const float* emb = (const float*)d_in[1];
    float* out = (float*)d_out;
    double* loss_ws = (double*)d_ws;
    float* ee_ws = (float*)((char*)d_ws + 256);
    unsigned short* ehi_ws  = (unsigned short*)((char*)d_ws + 4096);
    unsigned short* emid_ws = (unsigned short*)((char*)d_ws + 69632);

    hipMemsetAsync(d_ws, 0, sizeof(double), stream);
    hipLaunchKernelGGL(vq_prep, dim3(1), dim3(KCODES), 0, stream, emb, ee_ws, ehi_ws, emid_ws);

    dim3 grid(NPOS / MPOS);   // 2048
    dim3 block(NTHR);
    size_t shmem = 78984;
    hipLaunchKernelGGL(vq_main, grid, block, shmem, stream,
                       x, emb, out, loss_ws, ee_ws, ehi_ws, emid_ws);
    hipLaunchKernelGGL(vq_finalize, dim3(1), dim3(1), 0, stream,
                       (const double*)loss_ws, out);
}

// Round 11
// 248.894 us; speedup vs baseline: 1.5719x; 1.5719x over previous
//
#include <hip/hip_runtime.h>

typedef float f32x4 __attribute__((ext_vector_type(4)));
typedef __bf16 bf16x8 __attribute__((ext_vector_type(8)));
typedef short s16x8 __attribute__((ext_vector_type(8)));

// Problem constants
#define NPOS   524288         // 8*16*64*64
#define KCODES 512
#define CDIM   64
#define THW    65536          // 16*64*64
#define MPOS   128            // positions per block
#define NTHR   256            // 4 waves
#define NCH    8              // e-chunks of 64 codes (proven R9 granularity)
#define EPS2   4e-4f          // 2*epsilon certification threshold (proven R9)

// out layout (float32): [0, 33554432) quantized BCTHW; [33554432] loss; [33554433,+524288) indices
#define QOUT_N   33554432L
#define LOSSOFF  33554432L
#define IDX_OFF  33554433L

// ws: 0: double loss; 256: float eeg[512]; 4096: ushort ehi_g[8][512][8]; 69632: ushort emid_g[8][512][8]

__device__ inline unsigned int bf16_rne(unsigned int xb) {   // RN-even fp32->bf16 (no NaN/inf in data)
    return (xb + 0x7fffu + ((xb >> 16) & 1u)) >> 16;
}

#define GLOAD16(gp, lp) __builtin_amdgcn_global_load_lds( \
    (const __attribute__((address_space(1))) void*)(gp), \
    (__attribute__((address_space(3))) void*)(lp), 16, 0, 0)

__device__ inline f32x4 mf(s16x8 a, s16x8 b, f32x4 c) {
    return __builtin_amdgcn_mfma_f32_16x16x32_bf16(
        __builtin_bit_cast(bf16x8, a), __builtin_bit_cast(bf16x8, b), c, 0, 0, 0);
}

// bit-exact distance key (proven chain): (dist_bits<<32)|code ; a stride = MPOS
__device__ inline unsigned long long exact_key(const float* a, const float* ffl,
                                               const float* eel, const float* __restrict__ emb,
                                               int pos, int q) {
    const float* er = emb + (long)q * 64;
    float acc = __fmul_rn(a[pos], er[0]);
    #pragma unroll
    for (int c = 1; c < 64; ++c) acc = __fmaf_rn(a[c * MPOS + pos], er[c], acc);
    float t1 = __fadd_rn(ffl[pos], eel[q]);
    float d  = __fmaf_rn(acc, -2.0f, t1);
    return ((unsigned long long)__float_as_uint(d) << 32) | (unsigned)q;
}

// ---------- prep: exact ee[q] (numpy pairwise-8) + bf16 hi/mid split codebook ----------
extern "C" __global__ void vq_prep(const float* __restrict__ emb, float* __restrict__ ee,
                                   unsigned short* __restrict__ ehi, unsigned short* __restrict__ emid) {
    int q = threadIdx.x;               // 512 threads
    const float* er = emb + q * 64;
    float r[8];
    #pragma unroll
    for (int j = 0; j < 8; ++j) { float v = er[j]; r[j] = __fmul_rn(v, v); }
    #pragma unroll
    for (int t = 1; t < 8; ++t)
        #pragma unroll
        for (int j = 0; j < 8; ++j) { float v = er[t * 8 + j]; r[j] = __fadd_rn(r[j], __fmul_rn(v, v)); }
    float s0 = __fadd_rn(__fadd_rn(r[0], r[1]), __fadd_rn(r[2], r[3]));
    float s1 = __fadd_rn(__fadd_rn(r[4], r[5]), __fadd_rn(r[6], r[7]));
    ee[q] = __fadd_rn(s0, s1);
    #pragma unroll
    for (int c = 0; c < 64; ++c) {
        float x = er[c];
        unsigned int hb = bf16_rne(__float_as_uint(x));
        float hif = __uint_as_float(hb << 16);
        float m = __fsub_rn(x, hif);
        unsigned int mb = bf16_rne(__float_as_uint(m));
        long o = ((long)(c >> 3) * 512 + q) * 8 + (c & 7);   // [kg][code][8]
        ehi[o]  = (unsigned short)hb;
        emid[o] = (unsigned short)mb;
    }
}

// LDS layout (bytes), total 52808 -> 3 blocks/CU:
//   a     : 0      .. 32768   fp32 [64][128]
//   ehc   : 32768  .. +8192   ushort [8][64][8]   (hi chunk, 64 codes)
//   emc   : 40960  .. +8192   ushort [8][64][8]   (mid chunk)
//   eel   : 49152  .. +2048   float [512]
//   ffl   : 51200  .. +512    float [128]
//   kminl : 51712  .. +512    int [128]
//   wl    : 52224  .. +512    int [128]
//   wcnt  : 52736 (+8) | wred: 52744 (+32) | wsum: 52776 (+32)

extern "C" __global__ __launch_bounds__(NTHR, 3)
void vq_main(const float* __restrict__ x, const float* __restrict__ emb,
             float* __restrict__ out, double* __restrict__ lossws,
             const float* __restrict__ eeg,
             const unsigned short* __restrict__ ehi_g,
             const unsigned short* __restrict__ emid_g) {
    extern __shared__ char smem[];
    float*          a     = (float*)smem;
    unsigned short* ehc   = (unsigned short*)(smem + 32768);
    unsigned short* emc   = (unsigned short*)(smem + 40960);
    float*          eel   = (float*)(smem + 49152);
    float*          ffl   = (float*)(smem + 51200);
    int*            kminl = (int*)(smem + 51712);
    int*            wl    = (int*)(smem + 52224);
    int*            wcnt  = (int*)(smem + 52736);
    unsigned long long* wred = (unsigned long long*)(smem + 52744);
    double*         wsum  = (double*)(smem + 52776);

    const int tid  = threadIdx.x;
    const int lane = tid & 63;
    const int w    = tid >> 6;                    // wave 0..3 -> positions [w*32, w*32+32)
    const int blk  = blockIdx.x;
    const int b    = blk >> 9;                    // 512 blocks per batch element
    const int r0   = (blk & 511) << 7;
    const long n0  = (long)blk * MPOS;

    if (tid == 0) *wcnt = 0;

    // ---- phase 1: stage x-tile [64][128] + eel + e-chunk 0 (linear-dest gload_lds)
    const float* xb = x + (long)b * CDIM * THW + r0;
    #pragma unroll
    for (int k = 0; k < 8; ++k) {
        int g = tid + NTHR * k;                   // 16B-unit 0..2047
        int c = g >> 5, p4 = g & 31;
        GLOAD16(xb + (long)c * THW + p4 * 4, a + g * 4);
    }
    if (tid < 128) GLOAD16(eeg + tid * 4, eel + tid * 4);
    #pragma unroll
    for (int k = 0; k < 2; ++k) {
        int u = tid + NTHR * k, kg = u >> 6, cc = u & 63;
        long go = ((long)kg * 512 + cc) * 8;      // chunk 0
        GLOAD16(ehi_g + go, ehc + u * 8);
        GLOAD16(emid_g + go, emc + u * 8);
    }
    __syncthreads();   // drains vmcnt; a, eel, chunk 0 ready

    // ---- phase 2a: ff[p] exact (numpy pairwise-8; proven)
    if (tid < 128) {
        float rr[8];
        #pragma unroll
        for (int j = 0; j < 8; ++j) { float v = a[j * MPOS + tid]; rr[j] = __fmul_rn(v, v); }
        #pragma unroll
        for (int t = 1; t < 8; ++t)
            #pragma unroll
            for (int j = 0; j < 8; ++j) {
                float v = a[(t * 8 + j) * MPOS + tid];
                rr[j] = __fadd_rn(rr[j], __fmul_rn(v, v));
            }
        float s0 = __fadd_rn(__fadd_rn(rr[0], rr[1]), __fadd_rn(rr[2], rr[3]));
        float s1 = __fadd_rn(__fadd_rn(rr[4], rr[5]), __fadd_rn(rr[6], rr[7]));
        ffl[tid] = __fadd_rn(s0, s1);
    }

    // ---- phase 2b: per-wave A-fragments built in registers (split in-lane; proven R10 code)
    s16x8 fah[2][2], fam[2][2];
    #pragma unroll
    for (int mt = 0; mt < 2; ++mt)
        #pragma unroll
        for (int ks = 0; ks < 2; ++ks) {
            int kg  = ks * 4 + (lane >> 4);
            int pin = w * 32 + mt * 16 + (lane & 15);
            s16x8 hv, mv;
            #pragma unroll
            for (int j = 0; j < 8; ++j) {
                float xv = a[(kg * 8 + j) * MPOS + pin];
                unsigned int hb = bf16_rne(__float_as_uint(xv));
                float hif = __uint_as_float(hb << 16);
                float m = __fsub_rn(xv, hif);
                unsigned int mb = bf16_rne(__float_as_uint(m));
                hv[j] = (short)hb; mv[j] = (short)mb;
            }
            fah[mt][ks] = hv; fam[mt][ks] = mv;
        }
    __syncthreads();   // ffl ready for all

    float ffv[8];
    #pragma unroll
    for (int mt = 0; mt < 2; ++mt)
        #pragma unroll
        for (int rg = 0; rg < 4; ++rg)
            ffv[mt * 4 + rg] = ffl[w * 32 + mt * 16 + (lane >> 4) * 4 + rg];

    unsigned long long u1[8], u2[8];
    #pragma unroll
    for (int s = 0; s < 8; ++s) { u1[s] = ~0ull; u2[s] = ~0ull; }

    // ---- phase 4: MFMA distance scan, 8 chunks x 4 code-tiles (R9-proven structure)
    #pragma unroll 1
    for (int ch = 0; ch < NCH; ++ch) {
        if (ch) {
            __syncthreads();
            #pragma unroll
            for (int k = 0; k < 2; ++k) {
                int u = tid + NTHR * k, kg = u >> 6, cc = u & 63;
                long go = ((long)kg * 512 + (long)ch * 64 + cc) * 8;
                GLOAD16(ehi_g + go, ehc + u * 8);
                GLOAD16(emid_g + go, emc + u * 8);
            }
            __syncthreads();
        }
        #pragma unroll
        for (int nt = 0; nt < 4; ++nt) {
            int kg0 = lane >> 4, cin = nt * 16 + (lane & 15);
            s16x8 bh0 = *(const s16x8*)(ehc + ((kg0    ) * 64 + cin) * 8);
            s16x8 bh1 = *(const s16x8*)(ehc + ((kg0 + 4) * 64 + cin) * 8);
            s16x8 bm0 = *(const s16x8*)(emc + ((kg0    ) * 64 + cin) * 8);
            s16x8 bm1 = *(const s16x8*)(emc + ((kg0 + 4) * 64 + cin) * 8);
            unsigned code = ch * 64 + nt * 16 + (lane & 15);
            float eev = eel[code];
            #pragma unroll
            for (int mt = 0; mt < 2; ++mt) {
                f32x4 acc = {0.f, 0.f, 0.f, 0.f};
                acc = mf(fah[mt][0], bh0, acc);
                acc = mf(fah[mt][1], bh1, acc);
                acc = mf(fah[mt][0], bm0, acc);
                acc = mf(fah[mt][1], bm1, acc);
                acc = mf(fam[mt][0], bh0, acc);
                acc = mf(fam[mt][1], bh1, acc);
                #pragma unroll
                for (int rg = 0; rg < 4; ++rg) {
                    int s = mt * 4 + rg;
                    float t1 = __fadd_rn(ffv[s], eev);
                    float d  = __fmaf_rn(acc[rg], -2.0f, t1);
                    unsigned long long key = ((unsigned long long)__float_as_uint(d) << 32) | code;
                    bool c1 = key < u1[s];
                    unsigned long long nu2 = key < u2[s] ? key : u2[s];
                    u2[s] = c1 ? u1[s] : nu2;
                    u1[s] = c1 ? key : u1[s];
                }
            }
        }
    }

    // ---- phase 5: cross-lane top-3 merge (within 16 code-lanes) + certify (proven R9)
    #pragma unroll
    for (int s = 0; s < 8; ++s) {
        unsigned long long v1 = u1[s], v2 = u2[s];
        #pragma unroll
        for (int m = 1; m <= 8; m <<= 1) {
            unsigned long long p1 = __shfl_xor(v1, m, 64);
            unsigned long long p2 = __shfl_xor(v2, m, 64);
            unsigned long long lo  = v1 < p1 ? v1 : p1;
            unsigned long long hi  = v1 < p1 ? p1 : v1;
            unsigned long long mn2 = v2 < p2 ? v2 : p2;
            v1 = lo;
            v2 = hi < mn2 ? hi : mn2;
        }
        unsigned long long ex = (u1[s] != v1 && u1[s] != v2) ? u1[s]
                              : ((u2[s] != v1 && u2[s] != v2) ? u2[s] : ~0ull);
        #pragma unroll
        for (int m = 1; m <= 8; m <<= 1) {
            unsigned long long p = __shfl_xor(ex, m, 64);
            ex = p < ex ? p : ex;
        }
        if ((lane & 15) == 0) {
            int pos = w * 32 + (s >> 2) * 16 + (lane >> 4) * 4 + (s & 3);
            float d1 = __uint_as_float((unsigned)(v1 >> 32));
            float d2 = __uint_as_float((unsigned)(v2 >> 32));
            float d3 = __uint_as_float((unsigned)(ex >> 32));
            float thr = __fadd_rn(d1, EPS2);
            if (d2 > thr) {
                kminl[pos] = (int)(v1 & 0xffffffffu);
            } else if (d3 > thr) {
                unsigned long long ka = exact_key(a, ffl, eel, emb, pos, (int)(v1 & 0xffffffffu));
                unsigned long long kb = exact_key(a, ffl, eel, emb, pos, (int)(v2 & 0xffffffffu));
                unsigned long long km = ka < kb ? ka : kb;
                kminl[pos] = (int)(km & 0xffffffffu);
            } else {
                wl[atomicAdd(wcnt, 1)] = pos;
            }
        }
    }
    __syncthreads();

    // ---- phase 6: slow path — block-cooperative exact scan (256 threads x 2 codes)
    int nw = *wcnt;
    for (int i = 0; i < nw; ++i) {
        int pos = wl[i];
        unsigned long long ka = exact_key(a, ffl, eel, emb, pos, tid);
        unsigned long long kb = exact_key(a, ffl, eel, emb, pos, tid + 256);
        unsigned long long key = ka < kb ? ka : kb;
        #pragma unroll
        for (int m = 1; m < 64; m <<= 1) {
            unsigned long long p = __shfl_xor(key, m, 64);
            key = p < key ? p : key;
        }
        if (lane == 0) wred[w] = key;
        __syncthreads();
        if (tid == 0) {
            unsigned long long km = wred[0];
            #pragma unroll
            for (int j = 1; j < 4; ++j) km = wred[j] < km ? wred[j] : km;
            kminl[pos] = (int)(km & 0xffffffffu);
        }
        __syncthreads();
    }

    // ---- indices out (as float)
    if (tid < 128) out[IDX_OFF + n0 + tid] = (float)kminl[tid];

    // ---- quantized out (straight-through) + loss partial (proven R4 epilogue, 128-wide)
    double lacc = 0.0;
    {
        const int col = (tid & 31) * 4;
        int iv[4];
        #pragma unroll
        for (int jj = 0; jj < 4; ++jj) iv[jj] = kminl[col + jj];
        float* ob = out + (long)b * CDIM * THW + r0;
        #pragma unroll
        for (int k = 0; k < 8; ++k) {
            int c = (tid >> 5) + 8 * k;
            float4 xv = *(const float4*)(a + c * MPOS + col);
            float4 ov;
            float q0 = emb[iv[0] * 64 + c];
            float d0 = __fsub_rn(q0, xv.x); ov.x = __fadd_rn(xv.x, d0); lacc += (double)__fmul_rn(d0, d0);
            float q1 = emb[iv[1] * 64 + c];
            float d1 = __fsub_rn(q1, xv.y); ov.y = __fadd_rn(xv.y, d1); lacc += (double)__fmul_rn(d1, d1);
            float q2 = emb[iv[2] * 64 + c];
            float d2 = __fsub_rn(q2, xv.z); ov.z = __fadd_rn(xv.z, d2); lacc += (double)__fmul_rn(d2, d2);
            float q3 = emb[iv[3] * 64 + c];
            float d3 = __fsub_rn(q3, xv.w); ov.w = __fadd_rn(xv.w, d3); lacc += (double)__fmul_rn(d3, d3);
            *(float4*)(ob + (long)c * THW + col) = ov;
        }
    }
    #pragma unroll
    for (int m = 1; m < 64; m <<= 1) lacc += __shfl_xor(lacc, m, 64);
    if (lane == 0) wsum[w] = lacc;
    __syncthreads();
    if (tid == 0) {
        double s = wsum[0] + wsum[1] + wsum[2] + wsum[3];
        atomicAdd(lossws, s);
    }
}

extern "C" __global__ void vq_finalize(const double* __restrict__ lossws,
                                       float* __restrict__ out) {
    if (threadIdx.x == 0) {
        float m = (float)(lossws[0] / (double)QOUT_N);
        out[LOSSOFF] = __fadd_rn(m, __fmul_rn(0.025f, m));
    }
}

extern "C" void kernel_launch(void* const* d_in, const int* in_sizes, int n_in,
                              void* d_out, int out_size, void* d_ws, size_t ws_size,
                              hipStream_t stream) {
    const float* x   = (const float*)d_in[0];
    const float* emb = (const float*)d_in[1];
    float* out = (float*)d_out;
    double* loss_ws = (double*)d_ws;
    float* ee_ws = (float*)((char*)d_ws + 256);
    unsigned short* ehi_ws  = (unsigned short*)((char*)d_ws + 4096);
    unsigned short* emid_ws = (unsigned short*)((char*)d_ws + 69632);

    hipMemsetAsync(d_ws, 0, sizeof(double), stream);
    hipLaunchKernelGGL(vq_prep, dim3(1), dim3(KCODES), 0, stream, emb, ee_ws, ehi_ws, emid_ws);

    dim3 grid(NPOS / MPOS);   // 4096
    dim3 block(NTHR);
    size_t shmem = 52808;
    hipLaunchKernelGGL(vq_main, grid, block, shmem, stream,
                       x, emb, out, loss_ws, ee_ws, ehi_ws, emid_ws);
    hipLaunchKernelGGL(vq_finalize, dim3(1), dim3(1), 0, stream,
                       (const double*)loss_ws, out);
}